// Round 7
// baseline (242.017 us; speedup 1.0000x reference)
//
#include <hip/hip_runtime.h>
#include <hip/hip_bf16.h>

#define B_ 64
#define T_ 2048
#define D_ 512     // K dim of GEMM (KD=QD)
#define A_ 512     // attention dim (N of GEMM)
#define BM 128     // t-rows per block
#define BN 128     // a-cols per block (A split into 4 col-blocks)
#define BK 32      // K step
#define NSTEP (D_/BK)

typedef float f32x4_t __attribute__((ext_vector_type(4)));
typedef short bf16x8_t __attribute__((ext_vector_type(8)));

#define GLL16(g, l) __builtin_amdgcn_global_load_lds( \
    (const __attribute__((address_space(1))) void*)(g), \
    (__attribute__((address_space(3))) void*)(l), 16, 0, 0)

// ---------------- prep: q = query @ Wq + bq (fp32, exact) ----------------
__global__ void __launch_bounds__(256) qproj_kernel(
    const float* __restrict__ query, const float* __restrict__ Wq,
    const float* __restrict__ bq, float* __restrict__ qbuf) {
  __shared__ float qs[D_];
  const int b = blockIdx.x, tid = threadIdx.x;
  qs[tid] = query[b*D_ + tid];
  qs[tid+256] = query[b*D_ + tid + 256];
  __syncthreads();
  float a0 = bq[tid], a1 = bq[tid+256];
  for (int d = 0; d < D_; ++d) {
    const float qv = qs[d];
    a0 += qv * Wq[d*A_ + tid];
    a1 += qv * Wq[d*A_ + tid + 256];
  }
  qbuf[b*A_ + tid] = a0;
  qbuf[b*A_ + tid+256] = a1;
}

// ---- prep: Wk [D][A] fp32 -> bf16 slab (PLAIN layout) ----
// slab row (kb, a): 64 B = 4 slots of 8 bf16, slot c = k-octet kb*32 + c*8.
__global__ void __launch_bounds__(256) wkprep_kernel(
    const float* __restrict__ Wk, unsigned int* __restrict__ slab) {
  __shared__ float tile[32][65];
  const int kb = blockIdx.x >> 3;
  const int a0 = (blockIdx.x & 7) * 64;
  const int tid = threadIdx.x;
  for (int p = 0; p < 8; ++p) {
    const int idx = p*256 + tid;
    const int k = idx >> 6, al = idx & 63;
    tile[k][al] = Wk[(kb*32 + k)*A_ + a0 + al];
  }
  __syncthreads();
  const int al = tid >> 2, c = tid & 3;
  const int a = a0 + al;
  union { __hip_bfloat162 h[2]; uint2 u; } w0, w1;
  w0.h[0] = __float22bfloat162_rn(make_float2(tile[c*8+0][al], tile[c*8+1][al]));
  w0.h[1] = __float22bfloat162_rn(make_float2(tile[c*8+2][al], tile[c*8+3][al]));
  w1.h[0] = __float22bfloat162_rn(make_float2(tile[c*8+4][al], tile[c*8+5][al]));
  w1.h[1] = __float22bfloat162_rn(make_float2(tile[c*8+6][al], tile[c*8+7][al]));
  *(uint4*)(slab + (kb*512 + a)*16 + c*4) =
      make_uint4(w0.u.x, w0.u.y, w1.u.x, w1.u.y);
}

// ---- prep: keys [B][T][D] fp32 -> bf16 slab kslabA[b][kb][t][64 B] (PLAIN) ----
// Skips fully-masked 16-row tiles (t >= key_len rounded up).
__global__ void __launch_bounds__(256) kprep_kernel(
    const float* __restrict__ keys, const int* __restrict__ key_len,
    unsigned int* __restrict__ kslabA) {
  const int b = blockIdx.y;
  const int tt2 = blockIdx.x;              // 16-row tile
  if (tt2 * 16 >= key_len[b]) return;
  const int tid = threadIdx.x;
  const int tl = tid >> 4, kb = tid & 15;
  const int t = tt2*16 + tl;
  const float* src = keys + ((size_t)b*T_ + t)*D_ + kb*32;
  f32x4_t v[8];
  #pragma unroll
  for (int j = 0; j < 8; ++j) v[j] = *(const f32x4_t*)(src + j*4);
  unsigned int* dst = kslabA + ((size_t)(b*16 + kb)*T_ + t)*16;
  #pragma unroll
  for (int c = 0; c < 4; ++c) {
    union { __hip_bfloat162 h[2]; uint2 u; } w0, w1;
    w0.h[0] = __float22bfloat162_rn(make_float2(v[2*c][0],   v[2*c][1]));
    w0.h[1] = __float22bfloat162_rn(make_float2(v[2*c][2],   v[2*c][3]));
    w1.h[0] = __float22bfloat162_rn(make_float2(v[2*c+1][0], v[2*c+1][1]));
    w1.h[1] = __float22bfloat162_rn(make_float2(v[2*c+1][2], v[2*c+1][3]));
    *(uint4*)(dst + c*4) = make_uint4(w0.u.x, w0.u.y, w1.u.x, w1.u.y);
  }
}

// ------- fused energy: pure-GLL distance-2 pipeline, counted vmcnt, never drains -------
// LDS row r slot s holds k-octet s ^ ((r>>1)&3) (XOR from pre-swizzled global src;
// ds_read_b128 with this pattern measured 0 bank conflicts in R1).
__global__ void __launch_bounds__(256, 3) energy_kernel(
    const unsigned char* __restrict__ kslabA, const float* __restrict__ cover,
    const int* __restrict__ key_len, const unsigned char* __restrict__ slabB,
    const float* __restrict__ qbuf, const float* __restrict__ Wc,
    const float* __restrict__ Wo, float* __restrict__ epart) {
  __shared__ __align__(16) unsigned char Abuf[3][BM*64];   // 3 x 8 KB
  __shared__ __align__(16) unsigned char Bbuf[3][BN*64];   // 3 x 8 KB
  __shared__ float redbuf[4][64];

  const int d = blockIdx.x;                  // XCD-chunk swizzle
  const int logical = (d & 7) * 512 + (d >> 3);
  const int ct = logical & 3;
  const int tt = (logical >> 2) & 15;
  const int b  = logical >> 6;

  const int t0 = tt * BM;
  const int kl = key_len[b];
  if (t0 >= kl) return;

  const int tid = threadIdx.x;
  const int wid = tid >> 6;
  const int lane = tid & 63;
  const int lq = lane >> 4, lr = lane & 15;
  const int wm = wid >> 1, wn = wid & 1;     // 2x2 waves, 64x64 each

  // staging: thread tid covers LDS bytes tid*16 (+4096); row r = tid>>2, slot s = tid&3;
  // global src octet = s ^ ((r>>1)&3)  (same for +4096 since (r+64)>>1 keeps &3)
  const int sr = tid >> 2, ss = tid & 3;
  const int soff = sr*64 + ((ss ^ ((sr >> 1) & 3)) << 4);
  const unsigned char* asrc = kslabA + ((size_t)b*16*T_ + t0)*64 + soff;
  const unsigned char* bsrc = slabB + (size_t)ct*128*64 + soff;

  f32x4_t acc[4][4];
  #pragma unroll
  for (int i = 0; i < 4; ++i)
    #pragma unroll
    for (int j = 0; j < 4; ++j) acc[i][j] = 0.0f;

  int a_off[4], b_off[4];
  #pragma unroll
  for (int mf = 0; mf < 4; ++mf) {
    const int r = wm*64 + mf*16 + lr;
    a_off[mf] = r*64 + ((lq ^ ((r >> 1) & 3)) << 4);
  }
  #pragma unroll
  for (int nf = 0; nf < 4; ++nf) {
    const int r = wn*64 + nf*16 + lr;
    b_off[nf] = r*64 + ((lq ^ ((r >> 1) & 3)) << 4);
  }

  unsigned char *Ar = Abuf[0], *An = Abuf[1], *Aw = Abuf[2];
  unsigned char *Br = Bbuf[0], *Bn = Bbuf[1], *Bw = Bbuf[2];

  auto stage = [&](int ks, unsigned char* Ad, unsigned char* Bd) {
    const unsigned char* Ag = asrc + (size_t)ks * (T_*64);
    GLL16(Ag,        Ad + wid*1024);
    GLL16(Ag + 4096, Ad + 4096 + wid*1024);
    const unsigned char* Bg = bsrc + (size_t)ks * 32768;
    GLL16(Bg,        Bd + wid*1024);
    GLL16(Bg + 4096, Bd + 4096 + wid*1024);
  };

  // prologue: stage steps 0,1; wait only for step 0 (vmcnt(4) leaves step 1 in flight)
  stage(0, Ar, Br);
  stage(1, An, Bn);
  asm volatile("s_waitcnt vmcnt(4)" ::: "memory");
  __builtin_amdgcn_s_barrier();
  __builtin_amdgcn_sched_barrier(0);

  #pragma unroll 1
  for (int ks = 0; ks < NSTEP; ++ks) {
    if (ks + 2 < NSTEP) stage(ks + 2, Aw, Bw);
    bf16x8_t aF[4], bF[4];
    #pragma unroll
    for (int mf = 0; mf < 4; ++mf) aF[mf] = *(const bf16x8_t*)(Ar + a_off[mf]);
    #pragma unroll
    for (int nf = 0; nf < 4; ++nf) bF[nf] = *(const bf16x8_t*)(Br + b_off[nf]);
    #pragma unroll
    for (int mf = 0; mf < 4; ++mf)
      #pragma unroll
      for (int nf = 0; nf < 4; ++nf)
        acc[mf][nf] = __builtin_amdgcn_mfma_f32_16x16x32_bf16(aF[mf], bF[nf], acc[mf][nf], 0, 0, 0);
    if (ks + 1 < NSTEP) {
      // next step's GLLs were issued one full step ago; the only younger ops are
      // this step's 4 GLLs -> counted wait, never drains the pipeline.
      if (ks + 2 < NSTEP)
        asm volatile("s_waitcnt vmcnt(4)" ::: "memory");
      else
        asm volatile("s_waitcnt vmcnt(0)" ::: "memory");
      __builtin_amdgcn_s_barrier();
      __builtin_amdgcn_sched_barrier(0);
    }
    unsigned char* t;
    t = Ar; Ar = An; An = Aw; Aw = t;
    t = Br; Br = Bn; Bn = Bw; Bw = t;
  }

  // epilogue: pre = acc + q[n] + cover[t]*Wc[n]; ep += Wo[n]*tanh(pre)
  float cov[4][4];
  #pragma unroll
  for (int mf = 0; mf < 4; ++mf)
    #pragma unroll
    for (int j = 0; j < 4; ++j)
      cov[mf][j] = cover[(size_t)b*T_ + t0 + wm*64 + mf*16 + lq*4 + j];

  float ep[4][4];
  #pragma unroll
  for (int mf = 0; mf < 4; ++mf)
    #pragma unroll
    for (int j = 0; j < 4; ++j) ep[mf][j] = 0.f;

  #pragma unroll
  for (int nf = 0; nf < 4; ++nf) {
    const int n = ct*BN + wn*64 + nf*16 + lr;
    const float qv = qbuf[b*A_ + n];
    const float wc = Wc[n];
    const float wo = Wo[n];
    #pragma unroll
    for (int mf = 0; mf < 4; ++mf)
      #pragma unroll
      for (int j = 0; j < 4; ++j) {
        float p = acc[mf][nf][j] + qv + cov[mf][j] * wc;
        p = fminf(fmaxf(p, -15.f), 15.f);
        const float t2 = __expf(2.f * p);
        ep[mf][j] += wo * ((t2 - 1.f) * __builtin_amdgcn_rcpf(t2 + 1.f));
      }
  }
  #pragma unroll
  for (int mf = 0; mf < 4; ++mf)
    #pragma unroll
    for (int j = 0; j < 4; ++j) {
      float v = ep[mf][j];
      v += __shfl_xor(v, 1); v += __shfl_xor(v, 2);
      v += __shfl_xor(v, 4); v += __shfl_xor(v, 8);
      ep[mf][j] = v;
    }
  if (lr == 0) {
    #pragma unroll
    for (int mf = 0; mf < 4; ++mf)
      #pragma unroll
      for (int j = 0; j < 4; ++j)
        redbuf[wid][mf*16 + lq*4 + j] = ep[mf][j];
  }
  __syncthreads();
  if (tid < BM) {
    const int wmm = tid >> 6, rl = tid & 63;
    epart[((size_t)ct*B_ + b)*T_ + t0 + tid] = redbuf[wmm*2][rl] + redbuf[wmm*2+1][rl];
  }
}

// ------- fallback energy (R6 structure, fp32 keys, reg-pack A): used if ws too small -------
__global__ void __launch_bounds__(256, 3) energy_fb_kernel(
    const float* __restrict__ keys, const float* __restrict__ cover,
    const int* __restrict__ key_len, const unsigned char* __restrict__ slabB,
    const float* __restrict__ qbuf, const float* __restrict__ Wc,
    const float* __restrict__ Wo, float* __restrict__ epart) {
  __shared__ __align__(16) unsigned char Abuf[3][BM*64];
  __shared__ __align__(16) unsigned char Bbuf[3][BN*64];
  __shared__ float redbuf[4][64];

  const int d = blockIdx.x;
  const int logical = (d & 7) * 512 + (d >> 3);
  const int ct = logical & 3;
  const int tt = (logical >> 2) & 15;
  const int b  = logical >> 6;
  const int t0 = tt * BM;
  const int kl = key_len[b];
  if (t0 >= kl) return;

  const int tid = threadIdx.x;
  const int wid = tid >> 6;
  const int lane = tid & 63;
  const int lq = lane >> 4, lr = lane & 15;
  const int wm = wid >> 1, wn = wid & 1;

  const int sr = tid >> 1, sh = tid & 1;
  const float* agp = keys + ((size_t)b*T_ + t0 + sr)*D_ + sh*16;
  const int sx = (sr >> 1) & 3;
  const int sw0 = sr*64 + (((2*sh + 0) ^ sx) << 4);
  const int sw1 = sr*64 + (((2*sh + 1) ^ sx) << 4);

  const int ssr = tid >> 2, sss = tid & 3;
  const int soff = ssr*64 + ((sss ^ ((ssr >> 1) & 3)) << 4);
  const unsigned char* bsrc = slabB + (size_t)ct*128*64 + soff;

  f32x4_t acc[4][4];
  #pragma unroll
  for (int i = 0; i < 4; ++i)
    #pragma unroll
    for (int j = 0; j < 4; ++j) acc[i][j] = 0.0f;

  int a_off[4], b_off[4];
  #pragma unroll
  for (int mf = 0; mf < 4; ++mf) {
    const int r = wm*64 + mf*16 + lr;
    a_off[mf] = r*64 + ((lq ^ ((r >> 1) & 3)) << 4);
  }
  #pragma unroll
  for (int nf = 0; nf < 4; ++nf) {
    const int r = wn*64 + nf*16 + lr;
    b_off[nf] = r*64 + ((lq ^ ((r >> 1) & 3)) << 4);
  }

  f32x4_t pA[4];
  auto agload = [&](int ksrc) {
    const float* p = agp + ksrc*BK;
    pA[0] = *(const f32x4_t*)(p);
    pA[1] = *(const f32x4_t*)(p + 4);
    pA[2] = *(const f32x4_t*)(p + 8);
    pA[3] = *(const f32x4_t*)(p + 12);
  };
  auto bgll = [&](int ksrc, unsigned char* Bdst) {
    const unsigned char* g = bsrc + (size_t)ksrc*32768;
    GLL16(g,        Bdst + wid*1024);
    GLL16(g + 4096, Bdst + 4096 + wid*1024);
  };
  auto apack = [&](unsigned char* Adst) {
    union { __hip_bfloat162 h[2]; uint2 u; } q0, q1;
    q0.h[0] = __float22bfloat162_rn(make_float2(pA[0][0], pA[0][1]));
    q0.h[1] = __float22bfloat162_rn(make_float2(pA[0][2], pA[0][3]));
    q1.h[0] = __float22bfloat162_rn(make_float2(pA[1][0], pA[1][1]));
    q1.h[1] = __float22bfloat162_rn(make_float2(pA[1][2], pA[1][3]));
    *(uint4*)(Adst + sw0) = make_uint4(q0.u.x, q0.u.y, q1.u.x, q1.u.y);
    q0.h[0] = __float22bfloat162_rn(make_float2(pA[2][0], pA[2][1]));
    q0.h[1] = __float22bfloat162_rn(make_float2(pA[2][2], pA[2][3]));
    q1.h[0] = __float22bfloat162_rn(make_float2(pA[3][0], pA[3][1]));
    q1.h[1] = __float22bfloat162_rn(make_float2(pA[3][2], pA[3][3]));
    *(uint4*)(Adst + sw1) = make_uint4(q0.u.x, q0.u.y, q1.u.x, q1.u.y);
  };

  unsigned char *Ar = Abuf[0], *An = Abuf[1], *Aw = Abuf[2];
  unsigned char *Br = Bbuf[0], *Bn = Bbuf[1], *Bw = Bbuf[2];

  agload(0); bgll(0, Br); apack(Ar);
  agload(1); bgll(1, Bn); apack(An);
  asm volatile("s_waitcnt lgkmcnt(0)" ::: "memory");
  __builtin_amdgcn_s_barrier();
  __builtin_amdgcn_sched_barrier(0);

  for (int ks = 0; ks < NSTEP; ++ks) {
    const bool pre = (ks + 2 < NSTEP);
    if (pre) { agload(ks + 2); bgll(ks + 2, Bw); }
    bf16x8_t aF[4], bF[4];
    #pragma unroll
    for (int mf = 0; mf < 4; ++mf) aF[mf] = *(const bf16x8_t*)(Ar + a_off[mf]);
    #pragma unroll
    for (int nf = 0; nf < 4; ++nf) bF[nf] = *(const bf16x8_t*)(Br + b_off[nf]);
    #pragma unroll
    for (int mf = 0; mf < 4; ++mf)
      #pragma unroll
      for (int nf = 0; nf < 4; ++nf)
        acc[mf][nf] = __builtin_amdgcn_mfma_f32_16x16x32_bf16(aF[mf], bF[nf], acc[mf][nf], 0, 0, 0);
    if (pre) apack(Aw);
    if (ks + 1 < NSTEP) {
      if (!pre) asm volatile("s_waitcnt vmcnt(0)" ::: "memory");
      asm volatile("s_waitcnt lgkmcnt(0)" ::: "memory");
      __builtin_amdgcn_s_barrier();
      __builtin_amdgcn_sched_barrier(0);
    }
    unsigned char* t;
    t = Ar; Ar = An; An = Aw; Aw = t;
    t = Br; Br = Bn; Bn = Bw; Bw = t;
  }

  float cov[4][4];
  #pragma unroll
  for (int mf = 0; mf < 4; ++mf)
    #pragma unroll
    for (int j = 0; j < 4; ++j)
      cov[mf][j] = cover[(size_t)b*T_ + t0 + wm*64 + mf*16 + lq*4 + j];
  float ep[4][4];
  #pragma unroll
  for (int mf = 0; mf < 4; ++mf)
    #pragma unroll
    for (int j = 0; j < 4; ++j) ep[mf][j] = 0.f;
  #pragma unroll
  for (int nf = 0; nf < 4; ++nf) {
    const int n = ct*BN + wn*64 + nf*16 + lr;
    const float qv = qbuf[b*A_ + n];
    const float wc = Wc[n];
    const float wo = Wo[n];
    #pragma unroll
    for (int mf = 0; mf < 4; ++mf)
      #pragma unroll
      for (int j = 0; j < 4; ++j) {
        float p = acc[mf][nf][j] + qv + cov[mf][j] * wc;
        p = fminf(fmaxf(p, -15.f), 15.f);
        const float t2 = __expf(2.f * p);
        ep[mf][j] += wo * ((t2 - 1.f) * __builtin_amdgcn_rcpf(t2 + 1.f));
      }
  }
  #pragma unroll
  for (int mf = 0; mf < 4; ++mf)
    #pragma unroll
    for (int j = 0; j < 4; ++j) {
      float v = ep[mf][j];
      v += __shfl_xor(v, 1); v += __shfl_xor(v, 2);
      v += __shfl_xor(v, 4); v += __shfl_xor(v, 8);
      ep[mf][j] = v;
    }
  if (lr == 0) {
    #pragma unroll
    for (int mf = 0; mf < 4; ++mf)
      #pragma unroll
      for (int j = 0; j < 4; ++j)
        redbuf[wid][mf*16 + lq*4 + j] = ep[mf][j];
  }
  __syncthreads();
  if (tid < BM) {
    const int wmm = tid >> 6, rl = tid & 63;
    epart[((size_t)ct*B_ + b)*T_ + t0 + tid] = redbuf[wmm*2][rl] + redbuf[wmm*2+1][rl];
  }
}

// ---------------- masked softmax over T (sums 4 col-partials) ----------------
__global__ void __launch_bounds__(1024) softmax_kernel(
    const float* __restrict__ epart, const int* __restrict__ key_len,
    float* __restrict__ attn) {
  __shared__ float sredM[16];
  __shared__ float sredS[16];
  const int b = blockIdx.x, tid = threadIdx.x;
  const int kl = key_len[b];
  float e0 = -3.0e38f, e1 = -3.0e38f;
  if (tid < kl)
    e0 = epart[(size_t)b*T_ + tid] + epart[((size_t)B_ + b)*T_ + tid]
       + epart[((size_t)2*B_ + b)*T_ + tid] + epart[((size_t)3*B_ + b)*T_ + tid];
  if (tid + 1024 < kl)
    e1 = epart[(size_t)b*T_ + tid+1024] + epart[((size_t)B_ + b)*T_ + tid+1024]
       + epart[((size_t)2*B_ + b)*T_ + tid+1024] + epart[((size_t)3*B_ + b)*T_ + tid+1024];
  float m = fmaxf(e0, e1);
  for (int s = 32; s; s >>= 1) m = fmaxf(m, __shfl_xor(m, s));
  if ((tid & 63) == 0) sredM[tid >> 6] = m;
  __syncthreads();
  float M = -3.0e38f;
  #pragma unroll
  for (int i = 0; i < 16; ++i) M = fmaxf(M, sredM[i]);
  const float p0 = (tid < kl) ? __expf(e0 - M) : 0.f;
  const float p1 = (tid + 1024 < kl) ? __expf(e1 - M) : 0.f;
  float s = p0 + p1;
  for (int k = 32; k; k >>= 1) s += __shfl_xor(s, k);
  if ((tid & 63) == 0) sredS[tid >> 6] = s;
  __syncthreads();
  float S = 0.f;
  #pragma unroll
  for (int i = 0; i < 16; ++i) S += sredS[i];
  const float inv = 1.f / S;
  attn[b*T_ + tid] = p0 * inv;
  attn[b*T_ + tid + 1024] = p1 * inv;
}

// ---------------- context: partial sums over t-chunks, then combine ----------------
__global__ void __launch_bounds__(256) ctxpart_kernel(
    const float* __restrict__ value, const float* __restrict__ attn,
    const int* __restrict__ key_len, float* __restrict__ partial) {
  __shared__ float att_s[256];
  const int b = blockIdx.y, ch = blockIdx.x;
  const int tid = threadIdx.x;
  const int kl = key_len[b];
  const int tstart = ch * 256;
  const int tend = min(256, kl - tstart);
  float ax = 0.f, ay = 0.f;
  if (tend > 0) {
    att_s[tid] = attn[b*T_ + tstart + tid];
    __syncthreads();
    const float2* vp = (const float2*)(value + ((size_t)b*T_ + tstart)*D_) + tid;
    #pragma unroll 4
    for (int i = 0; i < tend; ++i) {
      const float w = att_s[i];
      const float2 v = vp[(size_t)i * 256];
      ax += w * v.x; ay += w * v.y;
    }
  }
  float2* pp = (float2*)(partial + (size_t)(b*8 + ch)*D_) + tid;
  *pp = make_float2(ax, ay);
}

__global__ void __launch_bounds__(256) ctxsum_kernel(
    const float* __restrict__ partial, float* __restrict__ ctx) {
  const int b = blockIdx.x, tid = threadIdx.x;
  float sx = 0.f, sy = 0.f;
  #pragma unroll
  for (int c = 0; c < 8; ++c) {
    const float2 v = *((const float2*)(partial + (size_t)(b*8 + c)*D_) + tid);
    sx += v.x; sy += v.y;
  }
  *((float2*)(ctx + (size_t)b*D_) + tid) = make_float2(sx, sy);
}

extern "C" void kernel_launch(void* const* d_in, const int* in_sizes, int n_in,
                              void* d_out, int out_size, void* d_ws, size_t ws_size,
                              hipStream_t stream) {
  const float* query  = (const float*)d_in[0];
  const float* keys   = (const float*)d_in[1];
  const float* value  = (const float*)d_in[2];
  const float* cover  = (const float*)d_in[3];
  const int*   key_len= (const int*)d_in[4];
  const float* Wq     = (const float*)d_in[5];
  const float* bq     = (const float*)d_in[6];
  const float* Wk     = (const float*)d_in[7];
  const float* Wc     = (const float*)d_in[8];
  const float* Wo     = (const float*)d_in[9];

  float* out = (float*)d_out;
  float* ctx_out  = out;            // [64,512]
  float* attn_out = out + B_*A_;    // [64,1,2048]

  char* ws = (char*)d_ws;
  float* qbuf    = (float*)ws;                              // 131072 B
  float* epart   = (float*)(ws + 131072);                   // 2097152 B
  float* partial = (float*)(ws + 131072 + 2097152);         // 1048576 B
  unsigned int* slabB = (unsigned int*)(ws + 131072 + 2097152 + 1048576);  // 524288 B
  const size_t small_end = 131072 + 2097152 + 1048576 + 524288;            // 3801088
  unsigned int* kslabA = (unsigned int*)(ws + small_end);   // 134217728 B
  const size_t need = small_end + 134217728ull;

  qproj_kernel<<<B_, 256, 0, stream>>>(query, Wq, bq, qbuf);
  wkprep_kernel<<<128, 256, 0, stream>>>(Wk, slabB);
  if (ws_size >= need) {
    kprep_kernel<<<dim3(T_/16, B_), 256, 0, stream>>>(keys, key_len, kslabA);
    energy_kernel<<<B_*(T_/BM)*(A_/BN), 256, 0, stream>>>(
        (const unsigned char*)kslabA, cover, key_len, (const unsigned char*)slabB,
        qbuf, Wc, Wo, epart);
  } else {
    energy_fb_kernel<<<B_*(T_/BM)*(A_/BN), 256, 0, stream>>>(
        keys, cover, key_len, (const unsigned char*)slabB, qbuf, Wc, Wo, epart);
  }
  softmax_kernel<<<B_, 1024, 0, stream>>>(epart, key_len, attn_out);
  ctxpart_kernel<<<dim3(8, B_), 256, 0, stream>>>(value, attn_out, key_len, partial);
  ctxsum_kernel<<<B_, 256, 0, stream>>>(partial, ctx_out);
}